// Round 4
// baseline (232.772 us; speedup 1.0000x reference)
//
#include <hip/hip_runtime.h>
#include <hip/hip_bf16.h>
#include <math.h>

#define NDIM 256
#define NROT 32640          // C(256,2)
#define NSEG 64
#define SEGLEN 510          // 64 * 510 == 32640 exactly
#define MATE (NDIM * NDIM)  // elements per plane
#define NODEE (2 * MATE)    // node = hi plane + lo plane (bf16 each)

typedef __bf16 bf16x4_t __attribute__((ext_vector_type(4)));
typedef __bf16 bf16x8_t __attribute__((ext_vector_type(8)));
typedef float f32x4_t __attribute__((ext_vector_type(4)));

// ---------------------------------------------------------------------------
// K2: build 64 segment products (510 rotations each) applied to I, fp32 in
// LDS. tile[rowblk][thread][8] layout -> b128 row streaming; 16-rotation
// batches with explicit A/B register double-buffering.
// Output: bf16 hi/lo planes. even seg -> TRANSPOSED ([c][k]), odd -> plain.
// ---------------------------------------------------------------------------

#define ROT1(RJ, CS) { float nri_ = fmaf((CS).x, ri, -((CS).y * (RJ))); \
                       (RJ) = fmaf((CS).y, ri, (CS).x * (RJ)); ri = nri_; }

#define LOAD16(P, JB, KK) \
    P##0 = *(const f32x4_t*)&tile[(JB)][t][0]; \
    P##1 = *(const f32x4_t*)&tile[(JB)][t][4]; \
    P##2 = *(const f32x4_t*)&tile[(JB) + 1][t][0]; \
    P##3 = *(const f32x4_t*)&tile[(JB) + 1][t][4]; \
    _Pragma("unroll") \
    for (int u = 0; u < 16; u++) P##c[u] = csl[(KK) + u];

#define COMP16(P, JB) \
    _Pragma("unroll") \
    for (int u = 0; u < 4; u++) ROT1(P##0[u], P##c[u]) \
    _Pragma("unroll") \
    for (int u = 0; u < 4; u++) ROT1(P##1[u], P##c[4 + u]) \
    _Pragma("unroll") \
    for (int u = 0; u < 4; u++) ROT1(P##2[u], P##c[8 + u]) \
    _Pragma("unroll") \
    for (int u = 0; u < 4; u++) ROT1(P##3[u], P##c[12 + u]) \
    *(f32x4_t*)&tile[(JB)][t][0] = P##0; \
    *(f32x4_t*)&tile[(JB)][t][4] = P##1; \
    *(f32x4_t*)&tile[(JB) + 1][t][0] = P##2; \
    *(f32x4_t*)&tile[(JB) + 1][t][4] = P##3;

__global__ __launch_bounds__(64, 1) void k_build(const float* __restrict__ rots,
                                                 __bf16* __restrict__ leaves) {
    __shared__ float tile[32][64][8];      // 64 KiB: row r at tile[r>>3][t][r&7]
    __shared__ float2 csl[SEGLEN + 16];
    const int t = threadIdx.x;             // 0..63
    const int seg = blockIdx.x >> 2;
    const int cg_ = blockIdx.x & 3;
    const int col = cg_ * 64 + t;
    const int kg0 = seg * SEGLEN;

    // fused sincos: stage this segment's (c,s) into LDS
    for (int u = t; u < SEGLEN; u += 64) {
        float th = rots[kg0 + u];
        float s, c;
        sincosf(th, &s, &c);
        csl[u] = make_float2(c, s);
    }
    for (int u = SEGLEN + t; u < SEGLEN + 16; u += 64) csl[u] = make_float2(1.f, 0.f);

    // init: identity columns for this column group (b128 writes)
    #pragma unroll
    for (int jb = 0; jb < 32; jb++) {
        f32x4_t z0 = {0.f, 0.f, 0.f, 0.f}, z1 = {0.f, 0.f, 0.f, 0.f};
        if ((col >> 3) == jb) {
            if ((col & 7) < 4) z0[col & 3] = 1.0f;
            else               z1[col & 3] = 1.0f;
        }
        *(f32x4_t*)&tile[jb][t][0] = z0;
        *(f32x4_t*)&tile[jb][t][4] = z1;
    }
    // single wave: LDS ops execute in order, no barrier needed

    int k = 0;
    int i = 0, cum = 0;
    while (cum + (NDIM - 1 - i) <= kg0) { cum += NDIM - 1 - i; i++; }
    int j = i + 1 + (kg0 - cum);

    float* T = &tile[0][0][0];
    #define TADDR(r) ((((r) >> 3) * 512) + t * 8 + ((r) & 7))

    while (k < SEGLEN) {
        float ri = T[TADDR(i)];
        int rem = min(NDIM - j, SEGLEN - k);

        // scalar peel to 8-row alignment
        int npeel = min((8 - (j & 7)) & 7, rem);
        for (int u = 0; u < npeel; u++) {
            float2 cs = csl[k];
            float rj = T[TADDR(j)];
            float nri = fmaf(cs.x, ri, -(cs.y * rj));
            T[TADDR(j)] = fmaf(cs.y, ri, cs.x * rj);
            ri = nri; j++; k++;
        }
        rem -= npeel;

        // 16-rotation batches, A/B double-buffered register prefetch
        if (rem >= 16) {
            int jb = j >> 3;
            f32x4_t A0, A1, A2, A3, B0, B1, B2, B3;
            float2 Ac[16], Bc[16];
            LOAD16(A, jb, k)
            while (rem >= 48) {
                LOAD16(B, jb + 2, k + 16)
                COMP16(A, jb)
                jb += 2; j += 16; k += 16; rem -= 16;
                LOAD16(A, jb + 2, k + 16)
                COMP16(B, jb)
                jb += 2; j += 16; k += 16; rem -= 16;
            }
            if (rem >= 32) {
                LOAD16(B, jb + 2, k + 16)
                COMP16(A, jb)
                jb += 2; j += 16; k += 16; rem -= 16;
                COMP16(B, jb)
                jb += 2; j += 16; k += 16; rem -= 16;
            } else {
                COMP16(A, jb)
                jb += 2; j += 16; k += 16; rem -= 16;
            }
        }

        // 8-rotation cleanup batch
        if (rem >= 8) {
            int jb = j >> 3;
            f32x4_t a0 = *(const f32x4_t*)&tile[jb][t][0];
            f32x4_t a1 = *(const f32x4_t*)&tile[jb][t][4];
            float2 cc[8];
            #pragma unroll
            for (int u = 0; u < 8; u++) cc[u] = csl[k + u];
            #pragma unroll
            for (int u = 0; u < 4; u++) ROT1(a0[u], cc[u])
            #pragma unroll
            for (int u = 0; u < 4; u++) ROT1(a1[u], cc[4 + u])
            *(f32x4_t*)&tile[jb][t][0] = a0;
            *(f32x4_t*)&tile[jb][t][4] = a1;
            j += 8; k += 8; rem -= 8;
        }

        // scalar tail
        while (rem > 0) {
            float2 cs = csl[k];
            float rj = T[TADDR(j)];
            float nri = fmaf(cs.x, ri, -(cs.y * rj));
            T[TADDR(j)] = fmaf(cs.y, ri, cs.x * rj);
            ri = nri; j++; k++; rem--;
        }

        T[TADDR(i)] = ri;
        if (j == NDIM) { i++; j = i + 1; }
    }
    #undef TADDR

    __bf16* hi = leaves + (size_t)seg * NODEE;
    __bf16* lo = hi + MATE;
    if (seg & 1) {
        // plain [r][col]: scalar 2B stores, coalesced across lanes
        for (int jb = 0; jb < 32; jb++) {
            f32x4_t v0 = *(const f32x4_t*)&tile[jb][t][0];
            f32x4_t v1 = *(const f32x4_t*)&tile[jb][t][4];
            #pragma unroll
            for (int u = 0; u < 8; u++) {
                float v = (u < 4) ? v0[u & 3] : v1[u & 3];
                __bf16 h = (__bf16)v;
                hi[(size_t)(jb * 8 + u) * NDIM + col] = h;
                lo[(size_t)(jb * 8 + u) * NDIM + col] = (__bf16)(v - (float)h);
            }
        }
    } else {
        // transposed [c][k]: contiguous bf16x8 stores per thread-row
        for (int jb = 0; jb < 32; jb++) {
            f32x4_t v0 = *(const f32x4_t*)&tile[jb][t][0];
            f32x4_t v1 = *(const f32x4_t*)&tile[jb][t][4];
            bf16x8_t vh, vl;
            #pragma unroll
            for (int u = 0; u < 8; u++) {
                float v = (u < 4) ? v0[u & 3] : v1[u & 3];
                __bf16 h = (__bf16)v;
                vh[u] = h;
                vl[u] = (__bf16)(v - (float)h);
            }
            *(bf16x8_t*)&hi[(size_t)col * NDIM + jb * 8] = vh;
            *(bf16x8_t*)&lo[(size_t)col * NDIM + jb * 8] = vl;
        }
    }
}

// ---------------------------------------------------------------------------
// K3a (NEW, for big levels np>=16): 128x128 output tile, K in 2 staged
// halves. Per pair only 4 blocks, each reading A-rows(128)+B-rows(128)
// hi/lo exactly once -> 1.0 MB/pair vs 2.1 MB for the 64x64 kernel (2.1x
// traffic cut). LDS 139 KB (4 planes x 128 x LDK2), 1 block/CU, 4 waves of
// 64x64, acc[4][4] persists across K-stages. Never the final level.
// node[p] = child[2p+1] @ child[2p]; A=child[2p] transposed, B plain.
// ---------------------------------------------------------------------------
#define LDK2 136  // padded LDS row (bf16); 272 B, 16B-aligned, bank-rotating
__global__ __launch_bounds__(256, 1) void k_combine2(const __bf16* __restrict__ src,
                                                     __bf16* __restrict__ dst) {
    __shared__ __bf16 planes[4][128 * LDK2];   // Bhi, Blo, Ahi, Alo (139264 B)

    const int p = blockIdx.x >> 2;
    const int qd = blockIdx.x & 3;
    const int rb = (qd >> 1) * 128;   // output row base (B rows)
    const int cb = (qd & 1) * 128;    // output col base (A rows, transposed)
    const __bf16* A = src + (size_t)(2 * p) * NODEE;       // transposed child
    const __bf16* B = src + (size_t)(2 * p + 1) * NODEE;   // plain child
    __bf16* Chi = dst + (size_t)p * NODEE;
    __bf16* Clo = Chi + MATE;
    const bool storeT = ((p & 1) == 0);

    const int t = threadIdx.x;
    const int wid = t >> 6, lane = t & 63;
    const int wr = (wid >> 1) * 64, wc = (wid & 1) * 64;
    const int lrow = lane & 15, kg = lane >> 4;

    const __bf16* plane_src[4] = {B, B + MATE, A, A + MATE};
    const int plane_row0[4] = {rb, rb, cb, cb};

    f32x4_t acc[4][4] = {};

    #pragma unroll
    for (int ks = 0; ks < 2; ks++) {
        if (ks) __syncthreads();     // protect LDS reuse from prior compute
        const int kb = ks * 128;
        // stage: 4 planes x 128 rows x 128 k (bf16) = 128 KB, 32 chunks/thread
        #pragma unroll
        for (int q = 0; q < 32; q++) {
            int g = q * 256 + t;
            int pl = g >> 11;            // 2048 16B-chunks per plane
            int c = g & 2047;
            int row = c >> 4, sg = c & 15;
            bf16x8_t v = *(const bf16x8_t*)&plane_src[pl][(size_t)(plane_row0[pl] + row) * NDIM + kb + sg * 8];
            *(bf16x8_t*)&planes[pl][row * LDK2 + sg * 8] = v;
        }
        __syncthreads();

        #pragma unroll
        for (int kc = 0; kc < 4; kc++) {
            bf16x8_t afh[4], afl[4], bfh[4], bfl[4];
            #pragma unroll
            for (int mt = 0; mt < 4; mt++) {
                int r = (wr + mt * 16 + lrow) * LDK2 + kc * 32 + kg * 8;
                afh[mt] = *(const bf16x8_t*)&planes[0][r];
                afl[mt] = *(const bf16x8_t*)&planes[1][r];
            }
            #pragma unroll
            for (int nt = 0; nt < 4; nt++) {
                int r = (wc + nt * 16 + lrow) * LDK2 + kc * 32 + kg * 8;
                bfh[nt] = *(const bf16x8_t*)&planes[2][r];
                bfl[nt] = *(const bf16x8_t*)&planes[3][r];
            }
            #pragma unroll
            for (int mt = 0; mt < 4; mt++)
                #pragma unroll
                for (int nt = 0; nt < 4; nt++) {
                    acc[mt][nt] = __builtin_amdgcn_mfma_f32_16x16x32_bf16(afh[mt], bfh[nt], acc[mt][nt], 0, 0, 0);
                    acc[mt][nt] = __builtin_amdgcn_mfma_f32_16x16x32_bf16(afh[mt], bfl[nt], acc[mt][nt], 0, 0, 0);
                    acc[mt][nt] = __builtin_amdgcn_mfma_f32_16x16x32_bf16(afl[mt], bfh[nt], acc[mt][nt], 0, 0, 0);
                }
        }
    }

    // C/D: col = lane&15, row = (lane>>4)*4 + reg
    #pragma unroll
    for (int mt = 0; mt < 4; mt++)
        #pragma unroll
        for (int nt = 0; nt < 4; nt++) {
            int grow = rb + wr + mt * 16 + kg * 4;
            int gcol = cb + wc + nt * 16 + lrow;
            if (storeT) {
                bf16x4_t vh, vl;
                #pragma unroll
                for (int r = 0; r < 4; r++) {
                    float v = acc[mt][nt][r];
                    __bf16 h = (__bf16)v;
                    vh[r] = h;
                    vl[r] = (__bf16)(v - (float)h);
                }
                *(bf16x4_t*)&Chi[(size_t)gcol * NDIM + grow] = vh;
                *(bf16x4_t*)&Clo[(size_t)gcol * NDIM + grow] = vl;
            } else {
                #pragma unroll
                for (int r = 0; r < 4; r++) {
                    float v = acc[mt][nt][r];
                    __bf16 h = (__bf16)v;
                    Chi[(size_t)(grow + r) * NDIM + gcol] = h;
                    Clo[(size_t)(grow + r) * NDIM + gcol] = (__bf16)(v - (float)h);
                }
            }
        }
}

// ---------------------------------------------------------------------------
// K3: one-shot tree combine (small levels). node[p] = child[2p+1] @ child[2p].
// Children as bf16 hi/lo planes; child[2p] transposed ([c][k]), child[2p+1]
// plain ([r][k]).  C ~= Bh@Ah + Bh@Al + Bl@Ah (fp32 acc).
// Block = 64x64 output over FULL K=256: stage 4 plane-tiles (132 KB LDS),
// ONE barrier, 96 MFMAs, store hi/lo (transposed if !final && p even).
// Grid = npairs*16, 256 threads (4 waves 2x2 of 32x32).
// ---------------------------------------------------------------------------
#define LDK 264   // padded LDS row (bf16); 528 B, 16B-aligned, bank-rotating
__global__ __launch_bounds__(256) void k_combine(const __bf16* __restrict__ src,
                                                 __bf16* __restrict__ dst,
                                                 int finalLevel) {
    __shared__ __bf16 planes[4][64 * LDK];   // Bhi, Blo, Ahi, Alo

    const int p = blockIdx.x >> 4;
    const int qd = blockIdx.x & 15;
    const int rbq = (qd >> 2) * 64;   // output row base (B rows)
    const int cbq = (qd & 3) * 64;    // output col base (A rows, transposed)
    const __bf16* A = src + (size_t)(2 * p) * NODEE;       // transposed child
    const __bf16* B = src + (size_t)(2 * p + 1) * NODEE;   // plain child
    __bf16* Chi = dst + (size_t)p * NODEE;
    __bf16* Clo = Chi + MATE;
    const bool storeT = (!finalLevel) && ((p & 1) == 0);

    const int t = threadIdx.x;
    const int wid = t >> 6, lane = t & 63;
    const int wr2 = (wid >> 1) * 32, wc2 = (wid & 1) * 32;
    const int lrow = lane & 15, kg = lane >> 4;

    const __bf16* plane_src[4] = {B, B + MATE, A, A + MATE};
    const int plane_row0[4] = {rbq, rbq, cbq, cbq};
    #pragma unroll
    for (int q = 0; q < 32; q++) {
        int g = q * 256 + t;
        int pl = g >> 11;            // 2048 16B-chunks per plane
        int c = g & 2047;
        int row = c >> 5, sg = c & 31;
        bf16x8_t v = *(const bf16x8_t*)&plane_src[pl][(size_t)(plane_row0[pl] + row) * NDIM + sg * 8];
        *(bf16x8_t*)&planes[pl][row * LDK + sg * 8] = v;
    }
    __syncthreads();

    f32x4_t acc[2][2] = {};
    #pragma unroll
    for (int kc = 0; kc < 8; kc++) {
        bf16x8_t afh[2], afl[2], bfh[2], bfl[2];
        #pragma unroll
        for (int mt = 0; mt < 2; mt++) {
            int r = (wr2 + mt * 16 + lrow) * LDK + kc * 32 + kg * 8;
            afh[mt] = *(const bf16x8_t*)&planes[0][r];
            afl[mt] = *(const bf16x8_t*)&planes[1][r];
        }
        #pragma unroll
        for (int nt = 0; nt < 2; nt++) {
            int r = (wc2 + nt * 16 + lrow) * LDK + kc * 32 + kg * 8;
            bfh[nt] = *(const bf16x8_t*)&planes[2][r];
            bfl[nt] = *(const bf16x8_t*)&planes[3][r];
        }
        #pragma unroll
        for (int mt = 0; mt < 2; mt++)
            #pragma unroll
            for (int nt = 0; nt < 2; nt++) {
                acc[mt][nt] = __builtin_amdgcn_mfma_f32_16x16x32_bf16(afh[mt], bfh[nt], acc[mt][nt], 0, 0, 0);
                acc[mt][nt] = __builtin_amdgcn_mfma_f32_16x16x32_bf16(afh[mt], bfl[nt], acc[mt][nt], 0, 0, 0);
                acc[mt][nt] = __builtin_amdgcn_mfma_f32_16x16x32_bf16(afl[mt], bfh[nt], acc[mt][nt], 0, 0, 0);
            }
    }

    // C/D: col = lane&15, row = (lane>>4)*4 + reg
    #pragma unroll
    for (int mt = 0; mt < 2; mt++)
        #pragma unroll
        for (int nt = 0; nt < 2; nt++) {
            int grow = rbq + wr2 + mt * 16 + kg * 4;
            int gcol = cbq + wc2 + nt * 16 + lrow;
            if (storeT) {
                bf16x4_t vh, vl;
                #pragma unroll
                for (int r = 0; r < 4; r++) {
                    float v = acc[mt][nt][r];
                    __bf16 h = (__bf16)v;
                    vh[r] = h;
                    vl[r] = (__bf16)(v - (float)h);
                }
                *(bf16x4_t*)&Chi[(size_t)gcol * NDIM + grow] = vh;
                *(bf16x4_t*)&Clo[(size_t)gcol * NDIM + grow] = vl;
            } else if (finalLevel) {
                #pragma unroll
                for (int r = 0; r < 4; r++)
                    Chi[(size_t)(grow + r) * NDIM + gcol] = (__bf16)acc[mt][nt][r];
            } else {
                #pragma unroll
                for (int r = 0; r < 4; r++) {
                    float v = acc[mt][nt][r];
                    __bf16 h = (__bf16)v;
                    Chi[(size_t)(grow + r) * NDIM + gcol] = h;
                    Clo[(size_t)(grow + r) * NDIM + gcol] = (__bf16)(v - (float)h);
                }
            }
        }
}

// ---------------------------------------------------------------------------
// K4: M-resident streaming GEMM. Y[b][c] = sum_k X[b][k]*Mhi[c][k].
// Each block stages HALF of Mhi (128 output-cols x 256 K = 66 KB LDS,
// 2 blocks/CU), ONE barrier, then 8 waves stream their own X row-slabs
// through registers (fp32->bf16 in-reg) with no further barriers and no X
// LDS round-trip. Grid 512: rg = bx & 255, ch = bx >> 8.
// ---------------------------------------------------------------------------
#define LDM 264   // padded LDS row (bf16); 528 B
__global__ __launch_bounds__(512, 1) void k_gemm(const float* __restrict__ X,
                                                 const __bf16* __restrict__ Mhi,
                                                 float* __restrict__ Y) {
    __shared__ __bf16 Ms[128 * LDM];   // 66 KB: output-cols [ch*128, ch*128+128), full K
    const int bx = blockIdx.x;
    const int rg = bx & 255;           // row group: rows [rg*256, rg*256+256)
    const int ch = bx >> 8;            // col half
    const int t = threadIdx.x;
    const int wid = t >> 6, lane = t & 63;
    const int lrow = lane & 15, kg = lane >> 4;

    // stage M half: 128 rows x 256 k = 64 KB -> 8 x bf16x8 per thread
    #pragma unroll
    for (int q = 0; q < 8; q++) {
        int g = q * 512 + t;           // 4096 chunks of 16 B
        int row = g >> 5, sg = g & 31;
        bf16x8_t v = *(const bf16x8_t*)&Mhi[(size_t)(ch * 128 + row) * 256 + sg * 8];
        *(bf16x8_t*)&Ms[row * LDM + sg * 8] = v;
    }
    __syncthreads();

    const int row0 = rg * 256 + wid * 32;   // this wave's 32 rows
    #pragma unroll
    for (int sl = 0; sl < 2; sl++) {
        const int rb = row0 + sl * 16;
        f32x4_t acc[8] = {};                 // nt = 0..7 (128 output cols)
        #pragma unroll
        for (int kc = 0; kc < 8; kc++) {
            // A-frag: row rb + lrow, k = kc*32 + kg*8 + 0..7
            const float* xp = &X[(size_t)(rb + lrow) * 256 + kc * 32 + kg * 8];
            f32x4_t x0 = *(const f32x4_t*)xp;
            f32x4_t x1 = *(const f32x4_t*)(xp + 4);
            bf16x8_t af;
            af[0] = (__bf16)x0.x; af[1] = (__bf16)x0.y;
            af[2] = (__bf16)x0.z; af[3] = (__bf16)x0.w;
            af[4] = (__bf16)x1.x; af[5] = (__bf16)x1.y;
            af[6] = (__bf16)x1.z; af[7] = (__bf16)x1.w;
            #pragma unroll
            for (int nt = 0; nt < 8; nt++) {
                bf16x8_t bf = *(const bf16x8_t*)&Ms[(nt * 16 + lrow) * LDM + kc * 32 + kg * 8];
                acc[nt] = __builtin_amdgcn_mfma_f32_16x16x32_bf16(af, bf, acc[nt], 0, 0, 0);
            }
        }
        // C/D: col = lane&15, row = (lane>>4)*4 + r
        #pragma unroll
        for (int nt = 0; nt < 8; nt++)
            #pragma unroll
            for (int r = 0; r < 4; r++)
                Y[(size_t)(rb + kg * 4 + r) * 256 + ch * 128 + nt * 16 + lrow] = acc[nt][r];
    }
}

// ---------------------------------------------------------------------------
// workspace: B0 = 64 nodes x 256 KB = 16 MB; B1 = 32 nodes x 256 KB = 8 MB.
// tree: B0(64) ->B1(32) ->B0(16) ->B1(8) ->B0(4) ->B1(2) ->B0(1=root, hi only)
// L0/L1 use the 128x128 low-traffic kernel; L2-L5 keep 64x64 (tail latency).
// ---------------------------------------------------------------------------
extern "C" void kernel_launch(void* const* d_in, const int* in_sizes, int n_in,
                              void* d_out, int out_size, void* d_ws, size_t ws_size,
                              hipStream_t stream) {
    const float* x = (const float*)d_in[0];
    const float* rots = (const float*)d_in[1];
    float* out = (float*)d_out;

    __bf16* B0 = (__bf16*)d_ws;
    __bf16* B1 = B0 + (size_t)NSEG * NODEE;

    k_build<<<NSEG * 4, 64, 0, stream>>>(rots, B0);
    k_combine2<<<32 * 4, 256, 0, stream>>>(B0, B1);       // L0: 32 pairs
    k_combine2<<<16 * 4, 256, 0, stream>>>(B1, B0);       // L1: 16 pairs
    k_combine<<<8 * 16, 256, 0, stream>>>(B0, B1, 0);     // L2
    k_combine<<<4 * 16, 256, 0, stream>>>(B1, B0, 0);     // L3
    k_combine<<<2 * 16, 256, 0, stream>>>(B0, B1, 0);     // L4
    k_combine<<<1 * 16, 256, 0, stream>>>(B1, B0, 1);     // L5 (root, hi only)
    k_gemm<<<512, 512, 0, stream>>>(x, B0, out);
}

// Round 5
// 218.839 us; speedup vs baseline: 1.0637x; 1.0637x over previous
//
#include <hip/hip_runtime.h>
#include <hip/hip_bf16.h>
#include <math.h>

#define NDIM 256
#define NROT 32640          // C(256,2)
#define NSEG 64
#define MATE (NDIM * NDIM)  // elements per plane
#define NODEE (2 * MATE)    // node = hi plane + lo plane (bf16 each)

// cost-balance model for k_build segment boundaries (run i has 255-i rots):
// cost(run i) = BF + BC*(255-i). BF/BC ~= scalar-per-run-overhead / vector
// per-rot cost ~= 80. Closed-form cumulative -> in-kernel binary search.
#define BF 1280
#define BC 16
#define CSLMAX 1104         // >= worst-case rots/segment (1084) + pad

typedef __bf16 bf16x4_t __attribute__((ext_vector_type(4)));
typedef __bf16 bf16x8_t __attribute__((ext_vector_type(8)));
typedef float f32x4_t __attribute__((ext_vector_type(4)));

// ---------------------------------------------------------------------------
// K2 v3: build 64 segment products applied to I, fp32 in LDS.
// NEW: segments are whole RUNS (run i = rotations (i,i+1..255)), boundaries
// cost-balanced so late short-run (scalar-path) segments get few rotations
// and early long-run (vector-path) segments get many. Duration was set by
// the scalar-dominated tail segments (VALUBusy 5%, uniform 510-rot split).
// Output: bf16 hi/lo planes. even seg -> TRANSPOSED ([c][k]), odd -> plain.
// ---------------------------------------------------------------------------

#define ROT1(RJ, CS) { float nri_ = fmaf((CS).x, ri, -((CS).y * (RJ))); \
                       (RJ) = fmaf((CS).y, ri, (CS).x * (RJ)); ri = nri_; }

#define LOAD16(P, JB, KK) \
    P##0 = *(const f32x4_t*)&tile[(JB)][t][0]; \
    P##1 = *(const f32x4_t*)&tile[(JB)][t][4]; \
    P##2 = *(const f32x4_t*)&tile[(JB) + 1][t][0]; \
    P##3 = *(const f32x4_t*)&tile[(JB) + 1][t][4]; \
    _Pragma("unroll") \
    for (int u = 0; u < 16; u++) P##c[u] = csl[(KK) + u];

#define COMP16(P, JB) \
    _Pragma("unroll") \
    for (int u = 0; u < 4; u++) ROT1(P##0[u], P##c[u]) \
    _Pragma("unroll") \
    for (int u = 0; u < 4; u++) ROT1(P##1[u], P##c[4 + u]) \
    _Pragma("unroll") \
    for (int u = 0; u < 4; u++) ROT1(P##2[u], P##c[8 + u]) \
    _Pragma("unroll") \
    for (int u = 0; u < 4; u++) ROT1(P##3[u], P##c[12 + u]) \
    *(f32x4_t*)&tile[(JB)][t][0] = P##0; \
    *(f32x4_t*)&tile[(JB)][t][4] = P##1; \
    *(f32x4_t*)&tile[(JB) + 1][t][0] = P##2; \
    *(f32x4_t*)&tile[(JB) + 1][t][4] = P##3;

__device__ __forceinline__ int run_off(int r) {        // rotations before run r
    return 255 * r - (r * (r - 1)) / 2;
}
__device__ __forceinline__ int cum_cost(int r) {       // model cost before run r
    return BF * r + BC * run_off(r);
}
__device__ __forceinline__ int seg_boundary(int s) {   // first run of segment s
    if (s <= 0) return 0;
    if (s >= NSEG) return 255;
    const long target = ((long)cum_cost(255) * s) / NSEG;
    int lo = 0, hi = 255;
    while (lo < hi) {
        int mid = (lo + hi) >> 1;
        if ((long)cum_cost(mid) >= target) hi = mid; else lo = mid + 1;
    }
    return lo;
}

__global__ __launch_bounds__(64, 1) void k_build(const float* __restrict__ rots,
                                                 __bf16* __restrict__ leaves) {
    __shared__ float tile[32][64][8];      // 64 KiB: row r at tile[r>>3][t][r&7]
    __shared__ float2 csl[CSLMAX];
    const int t = threadIdx.x;             // 0..63
    const int seg = blockIdx.x >> 2;
    const int cg_ = blockIdx.x & 3;
    const int col = cg_ * 64 + t;

    const int r0 = seg_boundary(seg);
    const int r1 = seg_boundary(seg + 1);
    const int kg0 = run_off(r0);
    const int nrot = run_off(r1) - kg0;

    // fused sincos: stage this segment's (c,s) into LDS
    for (int u = t; u < nrot; u += 64) {
        float th = rots[kg0 + u];
        float s, c;
        sincosf(th, &s, &c);
        csl[u] = make_float2(c, s);
    }
    for (int u = nrot + t; u < nrot + 16 && u < CSLMAX; u += 64) csl[u] = make_float2(1.f, 0.f);

    // init: identity columns for this column group (b128 writes)
    #pragma unroll
    for (int jb = 0; jb < 32; jb++) {
        f32x4_t z0 = {0.f, 0.f, 0.f, 0.f}, z1 = {0.f, 0.f, 0.f, 0.f};
        if ((col >> 3) == jb) {
            if ((col & 7) < 4) z0[col & 3] = 1.0f;
            else               z1[col & 3] = 1.0f;
        }
        *(f32x4_t*)&tile[jb][t][0] = z0;
        *(f32x4_t*)&tile[jb][t][4] = z1;
    }
    // single wave: LDS ops execute in order, no barrier needed

    float* T = &tile[0][0][0];
    #define TADDR(r) ((((r) >> 3) * 512) + t * 8 + ((r) & 7))

    int k = 0;
    for (int i = r0; i < r1; ++i) {       // whole runs only
        float ri = T[TADDR(i)];
        int j = i + 1;
        int rem = NDIM - j;

        // scalar peel to 8-row alignment
        int npeel = min((8 - (j & 7)) & 7, rem);
        for (int u = 0; u < npeel; u++) {
            float2 cs = csl[k];
            float rj = T[TADDR(j)];
            float nri = fmaf(cs.x, ri, -(cs.y * rj));
            T[TADDR(j)] = fmaf(cs.y, ri, cs.x * rj);
            ri = nri; j++; k++;
        }
        rem -= npeel;

        // 16-rotation batches, A/B double-buffered register prefetch
        if (rem >= 16) {
            int jb = j >> 3;
            f32x4_t A0, A1, A2, A3, B0, B1, B2, B3;
            float2 Ac[16], Bc[16];
            LOAD16(A, jb, k)
            while (rem >= 48) {
                LOAD16(B, jb + 2, k + 16)
                COMP16(A, jb)
                jb += 2; j += 16; k += 16; rem -= 16;
                LOAD16(A, jb + 2, k + 16)
                COMP16(B, jb)
                jb += 2; j += 16; k += 16; rem -= 16;
            }
            if (rem >= 32) {
                LOAD16(B, jb + 2, k + 16)
                COMP16(A, jb)
                jb += 2; j += 16; k += 16; rem -= 16;
                COMP16(B, jb)
                jb += 2; j += 16; k += 16; rem -= 16;
            } else {
                COMP16(A, jb)
                jb += 2; j += 16; k += 16; rem -= 16;
            }
        }

        // 8-rotation cleanup batch
        if (rem >= 8) {
            int jb = j >> 3;
            f32x4_t a0 = *(const f32x4_t*)&tile[jb][t][0];
            f32x4_t a1 = *(const f32x4_t*)&tile[jb][t][4];
            float2 cc[8];
            #pragma unroll
            for (int u = 0; u < 8; u++) cc[u] = csl[k + u];
            #pragma unroll
            for (int u = 0; u < 4; u++) ROT1(a0[u], cc[u])
            #pragma unroll
            for (int u = 0; u < 4; u++) ROT1(a1[u], cc[4 + u])
            *(f32x4_t*)&tile[jb][t][0] = a0;
            *(f32x4_t*)&tile[jb][t][4] = a1;
            j += 8; k += 8; rem -= 8;
        }

        // scalar tail
        while (rem > 0) {
            float2 cs = csl[k];
            float rj = T[TADDR(j)];
            float nri = fmaf(cs.x, ri, -(cs.y * rj));
            T[TADDR(j)] = fmaf(cs.y, ri, cs.x * rj);
            ri = nri; j++; k++; rem--;
        }

        T[TADDR(i)] = ri;
    }
    #undef TADDR

    __bf16* hi = leaves + (size_t)seg * NODEE;
    __bf16* lo = hi + MATE;
    if (seg & 1) {
        // plain [r][col]: scalar 2B stores, coalesced across lanes
        for (int jb = 0; jb < 32; jb++) {
            f32x4_t v0 = *(const f32x4_t*)&tile[jb][t][0];
            f32x4_t v1 = *(const f32x4_t*)&tile[jb][t][4];
            #pragma unroll
            for (int u = 0; u < 8; u++) {
                float v = (u < 4) ? v0[u & 3] : v1[u & 3];
                __bf16 h = (__bf16)v;
                hi[(size_t)(jb * 8 + u) * NDIM + col] = h;
                lo[(size_t)(jb * 8 + u) * NDIM + col] = (__bf16)(v - (float)h);
            }
        }
    } else {
        // transposed [c][k]: contiguous bf16x8 stores per thread-row
        for (int jb = 0; jb < 32; jb++) {
            f32x4_t v0 = *(const f32x4_t*)&tile[jb][t][0];
            f32x4_t v1 = *(const f32x4_t*)&tile[jb][t][4];
            bf16x8_t vh, vl;
            #pragma unroll
            for (int u = 0; u < 8; u++) {
                float v = (u < 4) ? v0[u & 3] : v1[u & 3];
                __bf16 h = (__bf16)v;
                vh[u] = h;
                vl[u] = (__bf16)(v - (float)h);
            }
            *(bf16x8_t*)&hi[(size_t)col * NDIM + jb * 8] = vh;
            *(bf16x8_t*)&lo[(size_t)col * NDIM + jb * 8] = vl;
        }
    }
}

// ---------------------------------------------------------------------------
// K3: one-shot tree combine (round-1 config, all levels — proven fastest).
// node[p] = child[2p+1] @ child[2p]; child[2p] transposed ([c][k]),
// child[2p+1] plain ([r][k]).  C ~= Bh@Ah + Bh@Al + Bl@Ah (fp32 acc).
// Block = 64x64 output over FULL K=256: stage 4 plane-tiles (132 KB LDS),
// ONE barrier, 96 MFMAs, store hi/lo (transposed if !final && p even).
// ---------------------------------------------------------------------------
#define LDK 264   // padded LDS row (bf16); 528 B, 16B-aligned, bank-rotating
__global__ __launch_bounds__(256) void k_combine(const __bf16* __restrict__ src,
                                                 __bf16* __restrict__ dst,
                                                 int finalLevel) {
    __shared__ __bf16 planes[4][64 * LDK];   // Bhi, Blo, Ahi, Alo

    const int p = blockIdx.x >> 4;
    const int qd = blockIdx.x & 15;
    const int rbq = (qd >> 2) * 64;   // output row base (B rows)
    const int cbq = (qd & 3) * 64;    // output col base (A rows, transposed)
    const __bf16* A = src + (size_t)(2 * p) * NODEE;       // transposed child
    const __bf16* B = src + (size_t)(2 * p + 1) * NODEE;   // plain child
    __bf16* Chi = dst + (size_t)p * NODEE;
    __bf16* Clo = Chi + MATE;
    const bool storeT = (!finalLevel) && ((p & 1) == 0);

    const int t = threadIdx.x;
    const int wid = t >> 6, lane = t & 63;
    const int wr2 = (wid >> 1) * 32, wc2 = (wid & 1) * 32;
    const int lrow = lane & 15, kg = lane >> 4;

    const __bf16* plane_src[4] = {B, B + MATE, A, A + MATE};
    const int plane_row0[4] = {rbq, rbq, cbq, cbq};
    #pragma unroll
    for (int q = 0; q < 32; q++) {
        int g = q * 256 + t;
        int pl = g >> 11;            // 2048 16B-chunks per plane
        int c = g & 2047;
        int row = c >> 5, sg = c & 31;
        bf16x8_t v = *(const bf16x8_t*)&plane_src[pl][(size_t)(plane_row0[pl] + row) * NDIM + sg * 8];
        *(bf16x8_t*)&planes[pl][row * LDK + sg * 8] = v;
    }
    __syncthreads();

    f32x4_t acc[2][2] = {};
    #pragma unroll
    for (int kc = 0; kc < 8; kc++) {
        bf16x8_t afh[2], afl[2], bfh[2], bfl[2];
        #pragma unroll
        for (int mt = 0; mt < 2; mt++) {
            int r = (wr2 + mt * 16 + lrow) * LDK + kc * 32 + kg * 8;
            afh[mt] = *(const bf16x8_t*)&planes[0][r];
            afl[mt] = *(const bf16x8_t*)&planes[1][r];
        }
        #pragma unroll
        for (int nt = 0; nt < 2; nt++) {
            int r = (wc2 + nt * 16 + lrow) * LDK + kc * 32 + kg * 8;
            bfh[nt] = *(const bf16x8_t*)&planes[2][r];
            bfl[nt] = *(const bf16x8_t*)&planes[3][r];
        }
        #pragma unroll
        for (int mt = 0; mt < 2; mt++)
            #pragma unroll
            for (int nt = 0; nt < 2; nt++) {
                acc[mt][nt] = __builtin_amdgcn_mfma_f32_16x16x32_bf16(afh[mt], bfh[nt], acc[mt][nt], 0, 0, 0);
                acc[mt][nt] = __builtin_amdgcn_mfma_f32_16x16x32_bf16(afh[mt], bfl[nt], acc[mt][nt], 0, 0, 0);
                acc[mt][nt] = __builtin_amdgcn_mfma_f32_16x16x32_bf16(afl[mt], bfh[nt], acc[mt][nt], 0, 0, 0);
            }
    }

    // C/D: col = lane&15, row = (lane>>4)*4 + reg
    #pragma unroll
    for (int mt = 0; mt < 2; mt++)
        #pragma unroll
        for (int nt = 0; nt < 2; nt++) {
            int grow = rbq + wr2 + mt * 16 + kg * 4;
            int gcol = cbq + wc2 + nt * 16 + lrow;
            if (storeT) {
                bf16x4_t vh, vl;
                #pragma unroll
                for (int r = 0; r < 4; r++) {
                    float v = acc[mt][nt][r];
                    __bf16 h = (__bf16)v;
                    vh[r] = h;
                    vl[r] = (__bf16)(v - (float)h);
                }
                *(bf16x4_t*)&Chi[(size_t)gcol * NDIM + grow] = vh;
                *(bf16x4_t*)&Clo[(size_t)gcol * NDIM + grow] = vl;
            } else if (finalLevel) {
                #pragma unroll
                for (int r = 0; r < 4; r++)
                    Chi[(size_t)(grow + r) * NDIM + gcol] = (__bf16)acc[mt][nt][r];
            } else {
                #pragma unroll
                for (int r = 0; r < 4; r++) {
                    float v = acc[mt][nt][r];
                    __bf16 h = (__bf16)v;
                    Chi[(size_t)(grow + r) * NDIM + gcol] = h;
                    Clo[(size_t)(grow + r) * NDIM + gcol] = (__bf16)(v - (float)h);
                }
            }
        }
}

// ---------------------------------------------------------------------------
// K4 v4: M-resident streaming GEMM with SLAB REGISTER PREFETCH.
// Y[b][c] = sum_k X[b][k]*Mhi[c][k]. Block stages half of Mhi (66 KB LDS),
// one barrier; each wave covers 32 rows as 2 slabs of 16; the ENTIRE next
// slab's X (16 b128/lane = 256 B/lane) is loaded to registers before the
// current slab computes -> ~16 KB/wave in flight (was 32 B) = Little's-law
// fix for the 2.9 TB/s plateau. ~170 VGPR, 8 waves/block, grid 512.
// ---------------------------------------------------------------------------
#define LDM 264   // padded LDS row (bf16); 528 B
__global__ __launch_bounds__(512, 1) void k_gemm(const float* __restrict__ X,
                                                 const __bf16* __restrict__ Mhi,
                                                 float* __restrict__ Y) {
    __shared__ __bf16 Ms[128 * LDM];   // output-cols [ch*128, ch*128+128), full K
    const int bx = blockIdx.x;
    const int rg = bx & 255;           // row group: rows [rg*256, rg*256+256)
    const int ch = bx >> 8;            // col half
    const int t = threadIdx.x;
    const int wid = t >> 6, lane = t & 63;
    const int lrow = lane & 15, kg = lane >> 4;

    // stage M half: 128 rows x 256 k = 64 KB -> 8 x bf16x8 per thread
    #pragma unroll
    for (int q = 0; q < 8; q++) {
        int g = q * 512 + t;           // 4096 chunks of 16 B
        int row = g >> 5, sg = g & 31;
        bf16x8_t v = *(const bf16x8_t*)&Mhi[(size_t)(ch * 128 + row) * 256 + sg * 8];
        *(bf16x8_t*)&Ms[row * LDM + sg * 8] = v;
    }

    const int row0 = rg * 256 + wid * 32;   // this wave's 32 rows (2 slabs of 16)
    const float* xb0 = &X[(size_t)(row0 + lrow) * 256 + kg * 8];
    const float* xb1 = xb0 + 16 * 256;

    // prefetch BOTH slabs' X before/while waiting on the staging barrier
    f32x4_t xa[16], xbq[16];
    #pragma unroll
    for (int kc = 0; kc < 8; kc++) {
        xa[2 * kc]     = *(const f32x4_t*)(xb0 + kc * 32);
        xa[2 * kc + 1] = *(const f32x4_t*)(xb0 + kc * 32 + 4);
    }
    #pragma unroll
    for (int kc = 0; kc < 8; kc++) {
        xbq[2 * kc]     = *(const f32x4_t*)(xb1 + kc * 32);
        xbq[2 * kc + 1] = *(const f32x4_t*)(xb1 + kc * 32 + 4);
    }
    __syncthreads();

    // slab 0
    {
        f32x4_t acc[8] = {};
        #pragma unroll
        for (int kc = 0; kc < 8; kc++) {
            bf16x8_t af;
            #pragma unroll
            for (int u = 0; u < 4; u++) {
                af[u]     = (__bf16)xa[2 * kc][u];
                af[4 + u] = (__bf16)xa[2 * kc + 1][u];
            }
            #pragma unroll
            for (int nt = 0; nt < 8; nt++) {
                bf16x8_t bf = *(const bf16x8_t*)&Ms[(nt * 16 + lrow) * LDM + kc * 32 + kg * 8];
                acc[nt] = __builtin_amdgcn_mfma_f32_16x16x32_bf16(af, bf, acc[nt], 0, 0, 0);
            }
        }
        #pragma unroll
        for (int nt = 0; nt < 8; nt++)
            #pragma unroll
            for (int r = 0; r < 4; r++)
                Y[(size_t)(row0 + kg * 4 + r) * 256 + ch * 128 + nt * 16 + lrow] = acc[nt][r];
    }
    // slab 1
    {
        f32x4_t acc[8] = {};
        #pragma unroll
        for (int kc = 0; kc < 8; kc++) {
            bf16x8_t af;
            #pragma unroll
            for (int u = 0; u < 4; u++) {
                af[u]     = (__bf16)xbq[2 * kc][u];
                af[4 + u] = (__bf16)xbq[2 * kc + 1][u];
            }
            #pragma unroll
            for (int nt = 0; nt < 8; nt++) {
                bf16x8_t bf = *(const bf16x8_t*)&Ms[(nt * 16 + lrow) * LDM + kc * 32 + kg * 8];
                acc[nt] = __builtin_amdgcn_mfma_f32_16x16x32_bf16(af, bf, acc[nt], 0, 0, 0);
            }
        }
        #pragma unroll
        for (int nt = 0; nt < 8; nt++)
            #pragma unroll
            for (int r = 0; r < 4; r++)
                Y[(size_t)(row0 + 16 + kg * 4 + r) * 256 + ch * 128 + nt * 16 + lrow] = acc[nt][r];
    }
}

// ---------------------------------------------------------------------------
// workspace: B0 = 64 nodes x 256 KB = 16 MB; B1 = 32 nodes x 256 KB = 8 MB.
// tree: B0(64) ->B1(32) ->B0(16) ->B1(8) ->B0(4) ->B1(2) ->B0(1=root, hi only)
// ---------------------------------------------------------------------------
extern "C" void kernel_launch(void* const* d_in, const int* in_sizes, int n_in,
                              void* d_out, int out_size, void* d_ws, size_t ws_size,
                              hipStream_t stream) {
    const float* x = (const float*)d_in[0];
    const float* rots = (const float*)d_in[1];
    float* out = (float*)d_out;

    __bf16* B0 = (__bf16*)d_ws;
    __bf16* B1 = B0 + (size_t)NSEG * NODEE;

    k_build<<<NSEG * 4, 64, 0, stream>>>(rots, B0);
    k_combine<<<32 * 16, 256, 0, stream>>>(B0, B1, 0);
    k_combine<<<16 * 16, 256, 0, stream>>>(B1, B0, 0);
    k_combine<<<8 * 16, 256, 0, stream>>>(B0, B1, 0);
    k_combine<<<4 * 16, 256, 0, stream>>>(B1, B0, 0);
    k_combine<<<2 * 16, 256, 0, stream>>>(B0, B1, 0);
    k_combine<<<1 * 16, 256, 0, stream>>>(B1, B0, 1);
    k_gemm<<<512, 512, 0, stream>>>(x, B0, out);
}